// Round 5
// baseline (330.882 us; speedup 1.0000x reference)
//
#include <hip/hip_runtime.h>
#include <hip/hip_bf16.h>

// Reassociated Tucker pipeline (fp32 in/out; bf16 internally):
//   y[b,t,o] = sum_j Z[b,t,j] * M[t,j,o]
//     Z[b,t,j] = sum_i x[b,t,i]   * in_core[i,j]
//     M[t,j,o] = sum_k W1[t,j,k]  * out_core[o,k]
//     W1[t,j,k]= sum_m task[t,m]  * tensor[m,j,k]
//
// v5: round-4 profile showed k_fused = 100us with EVERYTHING idle (occ 20.5%,
// mfma 3.3%, hbm 26%): latency-bound. Two fixes, one diagnosis:
//  (a) phase-1 rewritten as true double-buffer with RAW s_barrier + lgkm-only
//      waits (T3/T4): one barrier per 256-col tile, x-prefetch (depth 2) and
//      icT loads stay in flight across barriers; compiler emits counted vmcnt.
//      The old __syncthreads() drained vmcnt(0) 32x/block, exposing full HBM
//      latency every half-tile.
//  (b) 8-row blocks, grid 1024 -> 4 blocks/CU (was 2): 2x TLP. x loads become
//      512B-contiguous per row per instr. MFMA rows 8-15 idle (fine at 3% util).
// 3 dispatches: K_SETUP (W1 + icT), K2 (M_T), K_FUSED (Z in LDS -> y).

typedef __bf16 bf16;
typedef __bf16 bf16x8 __attribute__((ext_vector_type(8)));
typedef __bf16 bf16x4 __attribute__((ext_vector_type(4)));
typedef float  f32x4  __attribute__((ext_vector_type(4)));

__device__ __forceinline__ bf16x8 load_frag_bf16(const bf16* p) {
    return *reinterpret_cast<const bf16x8*>(p);
}

__device__ __forceinline__ bf16x8 load_frag_f32(const float* p) {
    f32x4 a = *reinterpret_cast<const f32x4*>(p);
    f32x4 b = *reinterpret_cast<const f32x4*>(p + 4);
    bf16x8 r;
    r[0] = (bf16)a[0]; r[1] = (bf16)a[1]; r[2] = (bf16)a[2]; r[3] = (bf16)a[3];
    r[4] = (bf16)b[0]; r[5] = (bf16)b[1]; r[6] = (bf16)b[2]; r[7] = (bf16)b[3];
    return r;
}

__device__ __forceinline__ f32x4 mfma16(bf16x8 a, bf16x8 b, f32x4 c) {
    return __builtin_amdgcn_mfma_f32_16x16x32_bf16(a, b, c, 0, 0, 0);
}

// lgkm-only barrier: LDS producer/consumer handoff WITHOUT draining vmcnt.
// asm "memory" clobber stops sinking of prior ds ops; sched_barrier(0) stops
// hoisting of following ds ops (rule #18 belt-and-suspenders).
__device__ __forceinline__ void bar_lgkm() {
    asm volatile("s_waitcnt lgkmcnt(0)" ::: "memory");
    __builtin_amdgcn_s_barrier();
    __builtin_amdgcn_sched_barrier(0);
}

// ---------------------------------------------------------------- K_SETUP
// grid 256 x 256. Blocks 0..127: W1[t][j][k] = sum_m task[t][m]*tensor[m][j][k].
// Blocks 128..255: icT[j][i] = bf16(in_core[i][j]) (16B stores, 1KB runs).
__global__ __launch_bounds__(256) void k_setup(
    const float* __restrict__ task,    // [8][64]
    const float* __restrict__ tensor,  // [64][64][64] (m, j, k)
    const float* __restrict__ in_core, // [4096][64]   (i, j)
    bf16* __restrict__ w1,             // [8][64][64]  (t, j, k)
    bf16* __restrict__ icT)            // [64][4096]   (j, i)
{
    int bid = blockIdx.x;
    if (bid < 128) {
        int t    = bid >> 4;
        int idx  = (bid & 15) * 256 + threadIdx.x;  // 0..4095
        int j    = idx >> 6;
        int k    = idx & 63;                        // lanes consecutive in k
        float acc = 0.f;
        #pragma unroll 8
        for (int m = 0; m < 64; ++m)
            acc += task[t * 64 + m] * tensor[(m * 64 + j) * 64 + k];
        w1[(t * 64 + j) * 64 + k] = (bf16)acc;
    } else {
        int idx = (bid - 128) * 256 + threadIdx.x;  // 0..32767
        int i0  = (idx & 511) * 8;
        int j   = idx >> 9;
        bf16x8 v;
        #pragma unroll
        for (int s = 0; s < 8; ++s)
            v[s] = (bf16)in_core[(size_t)(i0 + s) * 64 + j];
        *reinterpret_cast<bf16x8*>(icT + (size_t)j * 4096 + i0) = v;
    }
}

// ---------------------------------------------------------------- K2
// grid 512 x 256. M_T[t][o][j] = sum_k out_core[o][k]*W1[t][j][k].
__global__ __launch_bounds__(256) void k2_mt(
    const float* __restrict__ out_core, // [4096][64] (o, k) fp32
    const bf16* __restrict__ w1,        // [8][64][64] (t, j, k)
    bf16* __restrict__ mt)              // [8][4096][64] (t, o, j)
{
    int t    = blockIdx.x >> 6;
    int ot   = blockIdx.x & 63;
    int wave = threadIdx.x >> 6;
    int lane = threadIdx.x & 63;
    int m    = lane & 15;
    int q    = lane >> 4;
    int o0   = ot * 64 + wave * 16;

    f32x4 acc[4] = {};
    #pragma unroll
    for (int kc = 0; kc < 64; kc += 32) {
        bf16x8 a = load_frag_f32(out_core + (size_t)(o0 + m) * 64 + kc + q * 8);
        #pragma unroll
        for (int nt = 0; nt < 4; ++nt) {
            bf16x8 b = load_frag_bf16(w1 + (size_t)(t * 64 + nt * 16 + m) * 64 + kc + q * 8);
            acc[nt] = mfma16(a, b, acc[nt]);
        }
    }
    #pragma unroll
    for (int nt = 0; nt < 4; ++nt) {
        #pragma unroll
        for (int r = 0; r < 4; ++r) {
            int o = o0 + q * 4 + r;                  // C/D row = quad*4 + reg
            mt[(size_t)(t * 4096 + o) * 64 + nt * 16 + m] = (bf16)acc[nt][r];
        }
    }
}

// ---------------------------------------------------------------- K_FUSED
// grid 1024 x 256. Block: t = bid&7 (XCD-locked), 8 rows (b0+i)*8+t.
// Phase 1: Zb = X[8 rows][4096] * icT^T. Double-buffered 8x256 LDS tile,
//   one lgkm-only barrier per tile; depth-2 reg prefetch + per-tile icT
//   loads stay in flight across barriers (counted vmcnt by compiler).
// Phase 2: y[8 rows][4096] = Zb * M_T[t]; per-wave 1024 o; slab transpose
//   (wave-private, 8 rows) -> f32x4 stores, 512B contiguous per row.
__global__ __launch_bounds__(256) void k_fused(
    const float* __restrict__ x,   // [8192][4096] fp32 (rows = b*8+t)
    const bf16* __restrict__ icT,  // [64][4096] (j, i)
    const bf16* __restrict__ mt,   // [8][4096][64] (t, o, j)
    float* __restrict__ y)         // [1024][8][4096] fp32
{
    __shared__ bf16  xs[2][8 * 256];  // 8 KB total, double-buffered x tile
    __shared__ bf16  zb[16 * 80];     // 2.5 KB (rows 8-15 = dup of 0-7, unused)
    __shared__ float slab[4 * 1056];  // 16.9 KB: 4 waves x 8 rows x stride 132
    // total 27.6 KB -> LDS cap 5 blocks/CU; grid gives 4/CU.

    int t    = blockIdx.x & 7;        // one t per XCD (round-robin dispatch)
    int b0   = (blockIdx.x >> 3) * 8;
    int tid  = threadIdx.x;
    int r    = tid >> 5;              // staging row 0..7
    int c32  = tid & 31;              // staging col group (32 threads/row)
    int wave = tid >> 6;
    int lane = tid & 63;
    int m    = lane & 15;
    int q    = lane >> 4;
    int n0   = wave * 16;             // j-range of this wave (phase 1)

    const float* gsrc = x   + (size_t)((b0 + r) * 8 + t) * 4096;
    const bf16*  bbas = icT + (size_t)(n0 + m) * 4096;

    // stage: convert f32x4 pair -> swizzled bf16 tile row (row r, 256 cols)
    auto stage = [&](bf16* buf, const f32x4* v) {
        #pragma unroll
        for (int i = 0; i < 2; ++i) {
            bf16x4 w;
            w[0] = (bf16)v[i][0]; w[1] = (bf16)v[i][1];
            w[2] = (bf16)v[i][2]; w[3] = (bf16)v[i][3];
            int col = c32 * 4 + i * 128;
            int u   = (col >> 3) ^ r;             // XOR swizzle, 16B units
            *reinterpret_cast<bf16x4*>(&buf[r * 256 + u * 8 + (col & 7)]) = w;
        }
    };
    // compute: 8 MFMA from buf (A rows = m&7; rows 8-15 dup, discarded later)
    f32x4 acc = {};
    auto compute = [&](const bf16* buf, const bf16x8* bfr) {
        #pragma unroll
        for (int c = 0; c < 8; ++c) {
            int u = (c * 4 + q) ^ (m & 7);
            bf16x8 a = *reinterpret_cast<const bf16x8*>(&buf[(m & 7) * 256 + u * 8]);
            acc = mfma16(a, bfr[c], acc);
        }
    };

    // ---------------- phase 1 ----------------
    f32x4 vA[2], vB[2];
    #pragma unroll
    for (int i = 0; i < 2; ++i)
        vA[i] = *reinterpret_cast<const f32x4*>(gsrc + c32 * 4 + i * 128);
    #pragma unroll
    for (int i = 0; i < 2; ++i)
        vB[i] = *reinterpret_cast<const f32x4*>(gsrc + 256 + c32 * 4 + i * 128);

    stage(xs[0], vA);                 // tile 0 -> buf 0
    bar_lgkm();

    #pragma unroll 1
    for (int kt = 0; kt < 16; kt += 2) {
        // even tile kt: compute xs[0]; stage vB(tile kt+1)->xs[1]; prefetch kt+2->vA
        {
            bf16x8 bfr[8];
            #pragma unroll
            for (int c = 0; c < 8; ++c)
                bfr[c] = load_frag_bf16(bbas + kt * 256 + c * 32 + q * 8);
            if (kt + 2 < 16) {
                #pragma unroll
                for (int i = 0; i < 2; ++i)
                    vA[i] = *reinterpret_cast<const f32x4*>(
                        gsrc + (kt + 2) * 256 + c32 * 4 + i * 128);
            }
            stage(xs[1], vB);
            compute(xs[0], bfr);
            bar_lgkm();
        }
        // odd tile kt+1: compute xs[1]; stage vA(tile kt+2)->xs[0]; prefetch kt+3->vB
        {
            bf16x8 bfr[8];
            #pragma unroll
            for (int c = 0; c < 8; ++c)
                bfr[c] = load_frag_bf16(bbas + (kt + 1) * 256 + c * 32 + q * 8);
            if (kt + 3 < 16) {
                #pragma unroll
                for (int i = 0; i < 2; ++i)
                    vB[i] = *reinterpret_cast<const f32x4*>(
                        gsrc + (kt + 3) * 256 + c32 * 4 + i * 128);
            }
            if (kt + 2 < 16) stage(xs[0], vA);
            compute(xs[1], bfr);
            bar_lgkm();
        }
    }
    // acc[rr] = Z[row q*4+rr][j n0+m]; rows 8-15 are dups of 0-7 (harmless).
    #pragma unroll
    for (int rr = 0; rr < 4; ++rr)
        zb[(q * 4 + rr) * 80 + n0 + m] = (bf16)acc[rr];
    bar_lgkm();                        // Zb complete (cross-wave j ranges)

    // ---------------- phase 2 ----------------
    bf16x8 a_lo = *reinterpret_cast<const bf16x8*>(zb + m * 80 + q * 8);
    bf16x8 a_hi = *reinterpret_cast<const bf16x8*>(zb + m * 80 + 32 + q * 8);

    float* sw = slab + wave * 1056;                // wave-private slab (8 rows)
    const bf16* mbase = mt + ((size_t)t * 4096 + wave * 1024) * 64;

    #pragma unroll 1
    for (int g = 0; g < 8; ++g) {
        f32x4 acc2[8] = {};
        #pragma unroll
        for (int nt = 0; nt < 8; ++nt) {
            const bf16* bp = mbase + (size_t)(g * 128 + nt * 16 + m) * 64;
            bf16x8 blo = load_frag_bf16(bp + q * 8);        // L2 (XCD-local)
            bf16x8 bhi = load_frag_bf16(bp + 32 + q * 8);
            acc2[nt] = mfma16(a_lo, blo, acc2[nt]);
            acc2[nt] = mfma16(a_hi, bhi, acc2[nt]);
        }
        // transpose 8 valid rows (q<2) x 128 o through wave-private slab
        if (q < 2) {
            #pragma unroll
            for (int nt = 0; nt < 8; ++nt) {
                #pragma unroll
                for (int rr = 0; rr < 4; ++rr)
                    sw[(q * 4 + rr) * 132 + nt * 16 + m] = acc2[nt][rr];
            }
        }
        #pragma unroll
        for (int p = 0; p < 4; ++p) {
            int row = 2 * p + (lane >> 5);   // 2 rows x 512B contiguous / instr
            int cu  = lane & 31;
            f32x4 d = *reinterpret_cast<const f32x4*>(sw + row * 132 + cu * 4);
            *reinterpret_cast<f32x4*>(
                y + (size_t)((b0 + row) * 8 + t) * 4096 + wave * 1024 + g * 128 + cu * 4) = d;
        }
    }
}

// ----------------------------------------------------------------
extern "C" void kernel_launch(void* const* d_in, const int* in_sizes, int n_in,
                              void* d_out, int out_size, void* d_ws, size_t ws_size,
                              hipStream_t stream) {
    // setup_inputs order: x, tensor_core, task_core, in_core, out_core (all fp32)
    const float* x        = (const float*)d_in[0];
    const float* tensor_c = (const float*)d_in[1];
    const float* task_c   = (const float*)d_in[2];
    const float* in_c     = (const float*)d_in[3];
    const float* out_c    = (const float*)d_in[4];
    float* y = (float*)d_out;

    // Workspace layout (bytes): w1 64KB | icT 512KB | M_T 4MB
    char* ws = (char*)d_ws;
    bf16* w1  = (bf16*)ws;
    bf16* icT = (bf16*)(ws + (64 << 10));
    bf16* mtc = (bf16*)(ws + (64 << 10) + (512 << 10));

    k_setup<<<256,  256, 0, stream>>>(task_c, tensor_c, in_c, w1, icT);
    k2_mt  <<<512,  256, 0, stream>>>(out_c, w1, mtc);
    k_fused<<<1024, 256, 0, stream>>>(x, icT, mtc, y);
}

// Round 6
// 284.829 us; speedup vs baseline: 1.1617x; 1.1617x over previous
//
#include <hip/hip_runtime.h>
#include <hip/hip_bf16.h>

// Reassociated Tucker pipeline (fp32 in/out; bf16 internally):
//   y[b,t,o] = sum_j Z[b,t,j] * M[t,j,o]
//     Z[b,t,j] = sum_i x[b,t,i]   * in_core[i,j]
//     M[t,j,o] = sum_k W1[t,j,k]  * out_core[o,k]
//     W1[t,j,k]= sum_m task[t,m]  * tensor[m,j,k]
//
// v6: revert v5 (sched_barrier pinning + 8-row blocks regressed 100->157us;
// TLP was not the constraint). Back to v4 geometry (16 rows, 512 blocks),
// phase 1 rebuilt as the proven T3-minimum 2-phase schedule:
//   - global_load_lds width=16 stages raw f32 x tiles (async, no VGPR trip,
//     no cvt in critical section); swizzle via pre-swizzled per-lane SOURCE
//     address (LDS dest is lane-linear), inverse swizzle on ds_read.
//   - double-buffered LDS tile: ONE vmcnt(0)+s_barrier per tile (17/block
//     vs v4's 32 drains), no sched_barrier (m141 lesson).
//   - icT B-frags register-double-buffered one tile ahead: MFMA never waits
//     on global.
//   - f32->bf16 conversion moved to A-frag read path (VALU ~3% busy = free).
// LDS: phase-2 slab overlays the (dead) x-tile buffers -> 36.3 KB.
// Phase 2 identical to v4.

typedef __bf16 bf16;
typedef __bf16 bf16x8 __attribute__((ext_vector_type(8)));
typedef __bf16 bf16x4 __attribute__((ext_vector_type(4)));
typedef float  f32x4  __attribute__((ext_vector_type(4)));

__device__ __forceinline__ bf16x8 load_frag_bf16(const bf16* p) {
    return *reinterpret_cast<const bf16x8*>(p);
}

__device__ __forceinline__ bf16x8 load_frag_f32(const float* p) {
    f32x4 a = *reinterpret_cast<const f32x4*>(p);
    f32x4 b = *reinterpret_cast<const f32x4*>(p + 4);
    bf16x8 r;
    r[0] = (bf16)a[0]; r[1] = (bf16)a[1]; r[2] = (bf16)a[2]; r[3] = (bf16)a[3];
    r[4] = (bf16)b[0]; r[5] = (bf16)b[1]; r[6] = (bf16)b[2]; r[7] = (bf16)b[3];
    return r;
}

__device__ __forceinline__ f32x4 mfma16(bf16x8 a, bf16x8 b, f32x4 c) {
    return __builtin_amdgcn_mfma_f32_16x16x32_bf16(a, b, c, 0, 0, 0);
}

// Async global->LDS, 16B per lane. LDS dest is wave-uniform base + lane*16.
__device__ __forceinline__ void gl_lds16(const float* g, void* l) {
    __builtin_amdgcn_global_load_lds(
        (const __attribute__((address_space(1))) void*)g,
        (__attribute__((address_space(3))) void*)l, 16, 0, 0);
}

// One barrier per tile: drain the staged gload_lds (+B-frag prefetch, which
// had the whole compute phase to finish), then sync. Memory clobber keeps
// loads from sinking below / ds_reads from hoisting above. NO sched_barrier.
__device__ __forceinline__ void tile_bar() {
    asm volatile("s_waitcnt vmcnt(0)\n\ts_barrier" ::: "memory");
}

// ---------------------------------------------------------------- K_SETUP
// grid 256 x 256. Blocks 0..127: W1[t][j][k] = sum_m task[t][m]*tensor[m][j][k].
// Blocks 128..255: icT[j][i] = bf16(in_core[i][j]) (16B stores, 1KB runs).
__global__ __launch_bounds__(256) void k_setup(
    const float* __restrict__ task,    // [8][64]
    const float* __restrict__ tensor,  // [64][64][64] (m, j, k)
    const float* __restrict__ in_core, // [4096][64]   (i, j)
    bf16* __restrict__ w1,             // [8][64][64]  (t, j, k)
    bf16* __restrict__ icT)            // [64][4096]   (j, i)
{
    int bid = blockIdx.x;
    if (bid < 128) {
        int t    = bid >> 4;
        int idx  = (bid & 15) * 256 + threadIdx.x;  // 0..4095
        int j    = idx >> 6;
        int k    = idx & 63;                        // lanes consecutive in k
        float acc = 0.f;
        #pragma unroll 8
        for (int m = 0; m < 64; ++m)
            acc += task[t * 64 + m] * tensor[(m * 64 + j) * 64 + k];
        w1[(t * 64 + j) * 64 + k] = (bf16)acc;
    } else {
        int idx = (bid - 128) * 256 + threadIdx.x;  // 0..32767
        int i0  = (idx & 511) * 8;
        int j   = idx >> 9;
        bf16x8 v;
        #pragma unroll
        for (int s = 0; s < 8; ++s)
            v[s] = (bf16)in_core[(size_t)(i0 + s) * 64 + j];
        *reinterpret_cast<bf16x8*>(icT + (size_t)j * 4096 + i0) = v;
    }
}

// ---------------------------------------------------------------- K2
// grid 512 x 256. M_T[t][o][j] = sum_k out_core[o][k]*W1[t][j][k].
__global__ __launch_bounds__(256) void k2_mt(
    const float* __restrict__ out_core, // [4096][64] (o, k) fp32
    const bf16* __restrict__ w1,        // [8][64][64] (t, j, k)
    bf16* __restrict__ mt)              // [8][4096][64] (t, o, j)
{
    int t    = blockIdx.x >> 6;
    int ot   = blockIdx.x & 63;
    int wave = threadIdx.x >> 6;
    int lane = threadIdx.x & 63;
    int m    = lane & 15;
    int q    = lane >> 4;
    int o0   = ot * 64 + wave * 16;

    f32x4 acc[4] = {};
    #pragma unroll
    for (int kc = 0; kc < 64; kc += 32) {
        bf16x8 a = load_frag_f32(out_core + (size_t)(o0 + m) * 64 + kc + q * 8);
        #pragma unroll
        for (int nt = 0; nt < 4; ++nt) {
            bf16x8 b = load_frag_bf16(w1 + (size_t)(t * 64 + nt * 16 + m) * 64 + kc + q * 8);
            acc[nt] = mfma16(a, b, acc[nt]);
        }
    }
    #pragma unroll
    for (int nt = 0; nt < 4; ++nt) {
        #pragma unroll
        for (int r = 0; r < 4; ++r) {
            int o = o0 + q * 4 + r;                  // C/D row = quad*4 + reg
            mt[(size_t)(t * 4096 + o) * 64 + nt * 16 + m] = (bf16)acc[nt][r];
        }
    }
}

// ---------------------------------------------------------------- K_FUSED
// grid 512 x 256. Block: t = bid&7 (XCD-locked), 16 rows (b0+i)*8+t.
// Phase 1: Zb = X[16 rows][4096] * icT^T.
//   Tile = 16 rows x 256 f32 (16 KB), double-buffered via global_load_lds.
//   LDS tile layout (lane-linear, forced by gload_lds): f32 index =
//   i*1024 + tid*4 for staging instr i = col-block (64 f32). Thread tid ->
//   (row = tid>>4, chunk c16 = tid&15); source col chunk PRE-SWIZZLED:
//   cc = c16 ^ row, so LDS slot s of row r holds global chunk s^r ->
//   read at slot (chunk ^ row) = inverse swizzle; banks ~2-way (free).
//   Loop: {stage(next, buf^1) || loadfrags(next) || compute(cur)} ; vmcnt(0)
//   + barrier. 17 barriers/block (v4: 32 full drains).
// Phase 2: y[16 rows][4096] = Zb * M_T[t]; identical to v4 (slab transpose,
//   512B-contiguous f32x4 stores); slab overlays the x-tile pool.
__global__ __launch_bounds__(256) void k_fused(
    const float* __restrict__ x,   // [8192][4096] fp32 (rows = b*8+t)
    const bf16* __restrict__ icT,  // [64][4096] (j, i)
    const bf16* __restrict__ mt,   // [8][4096][64] (t, o, j)
    float* __restrict__ y)         // [1024][8][4096] fp32
{
    // pool: phase 1 = two 16 KB f32 x-tiles; phase 2 = 33 KB slab.
    __shared__ __align__(16) char pool[4 * 2112 * 4];   // 33792 B
    __shared__ bf16 zb[16 * 80];                        // 2.5 KB

    float* xsf0 = (float*)pool;           // [4096] f32, tile buffer 0
    float* xsf1 = (float*)pool + 4096;    // tile buffer 1
    float* slab = (float*)pool;           // phase-2 reuse (xsf dead by then)

    int t    = blockIdx.x & 7;            // one t per XCD (round-robin dispatch)
    int b0   = (blockIdx.x >> 3) * 16;
    int tid  = threadIdx.x;
    int row  = tid >> 4;                  // staging row 0..15
    int cc   = (tid & 15) ^ row;          // pre-swizzled source chunk
    int wave = tid >> 6;
    int lane = tid & 63;
    int m    = lane & 15;
    int q    = lane >> 4;
    int n0   = wave * 16;                 // j-range of this wave (phase 1)

    // per-lane global source (row, swizzled chunk)
    const float* xrow = x + (size_t)((b0 + row) * 8 + t) * 4096 + cc * 4;
    const bf16*  bbas = icT + (size_t)(n0 + m) * 4096;

    // stage tile kt into LDS buffer (4 x gload_lds dwordx4; dest wave-uniform)
    auto stage = [&](int kt, float* buf) {
        char* lb = (char*)buf + wave * 1024;
        const float* g = xrow + (size_t)kt * 256;
        #pragma unroll
        for (int i = 0; i < 4; ++i)
            gl_lds16(g + i * 64, lb + i * 4096);
    };
    // prefetch tile kt's 8 icT B-frags into registers
    auto loadfrags = [&](bf16x8* f, int kt) {
        #pragma unroll
        for (int c = 0; c < 8; ++c)
            f[c] = load_frag_bf16(bbas + kt * 256 + c * 32 + q * 8);
    };
    // 8 MFMA from buf: A-frag = row m, f32 cols c*32+q*8..+8 (inv-swizzled)
    f32x4 acc = {};
    auto compute = [&](const float* buf, const bf16x8* f) {
        #pragma unroll
        for (int c = 0; c < 8; ++c) {
            int ib = c >> 1;                        // 64-f32 col block
            int h2 = ((c & 1) * 4 + q) * 2;         // first 16B chunk
            const float* base = buf + ib * 1024 + m * 64;
            f32x4 a0 = *reinterpret_cast<const f32x4*>(base + ((h2    ) ^ m) * 4);
            f32x4 a1 = *reinterpret_cast<const f32x4*>(base + ((h2 + 1) ^ m) * 4);
            bf16x8 a;
            a[0] = (bf16)a0[0]; a[1] = (bf16)a0[1];
            a[2] = (bf16)a0[2]; a[3] = (bf16)a0[3];
            a[4] = (bf16)a1[0]; a[5] = (bf16)a1[1];
            a[6] = (bf16)a1[2]; a[7] = (bf16)a1[3];
            acc = mfma16(a, f[c], acc);
        }
    };

    // ---------------- phase 1 ----------------
    bf16x8 bfrA[8], bfrB[8];
    loadfrags(bfrA, 0);
    stage(0, xsf0);
    tile_bar();

    #pragma unroll 1
    for (int kt = 0; kt < 16; kt += 2) {
        // even tile kt (buf0): stage kt+1 -> buf1, prefetch frags kt+1
        stage(kt + 1, xsf1);
        loadfrags(bfrB, kt + 1);
        compute(xsf0, bfrA);
        tile_bar();
        // odd tile kt+1 (buf1): stage kt+2 -> buf0, prefetch frags kt+2
        if (kt + 2 < 16) {
            stage(kt + 2, xsf0);
            loadfrags(bfrA, kt + 2);
        }
        compute(xsf1, bfrB);
        tile_bar();
    }
    // acc[rr] = Z[row q*4+rr][j n0+m]  (D-row <-> A-row, D-col <-> B-row)
    #pragma unroll
    for (int rr = 0; rr < 4; ++rr)
        zb[(q * 4 + rr) * 80 + n0 + m] = (bf16)acc[rr];
    __syncthreads();                       // Zb complete; xsf dead -> slab live

    // ---------------- phase 2 (v4-identical) ----------------
    bf16x8 a_lo = *reinterpret_cast<const bf16x8*>(zb + m * 80 + q * 8);
    bf16x8 a_hi = *reinterpret_cast<const bf16x8*>(zb + m * 80 + 32 + q * 8);

    float* sw = slab + wave * 2112;               // wave-private slab
    const bf16* mbase = mt + ((size_t)t * 4096 + wave * 1024) * 64;

    #pragma unroll 1
    for (int g = 0; g < 8; ++g) {
        f32x4 acc2[8] = {};
        #pragma unroll
        for (int nt = 0; nt < 8; ++nt) {
            const bf16* bp = mbase + (size_t)(g * 128 + nt * 16 + m) * 64;
            bf16x8 blo = load_frag_bf16(bp + q * 8);        // L2 (XCD-local)
            bf16x8 bhi = load_frag_bf16(bp + 32 + q * 8);
            acc2[nt] = mfma16(a_lo, blo, acc2[nt]);
            acc2[nt] = mfma16(a_hi, bhi, acc2[nt]);
        }
        // transpose 16 rows x 128 o through wave-private slab
        #pragma unroll
        for (int nt = 0; nt < 8; ++nt) {
            #pragma unroll
            for (int rr = 0; rr < 4; ++rr)
                sw[(q * 4 + rr) * 132 + nt * 16 + m] = acc2[nt][rr];
        }
        #pragma unroll
        for (int p = 0; p < 8; ++p) {
            int rr = 2 * p + (lane >> 5);   // 2 rows x 512B contiguous / instr
            int cu = lane & 31;
            f32x4 d = *reinterpret_cast<const f32x4*>(sw + rr * 132 + cu * 4);
            *reinterpret_cast<f32x4*>(
                y + (size_t)((b0 + rr) * 8 + t) * 4096 + wave * 1024 + g * 128 + cu * 4) = d;
        }
    }
}

// ----------------------------------------------------------------
extern "C" void kernel_launch(void* const* d_in, const int* in_sizes, int n_in,
                              void* d_out, int out_size, void* d_ws, size_t ws_size,
                              hipStream_t stream) {
    // setup_inputs order: x, tensor_core, task_core, in_core, out_core (all fp32)
    const float* x        = (const float*)d_in[0];
    const float* tensor_c = (const float*)d_in[1];
    const float* task_c   = (const float*)d_in[2];
    const float* in_c     = (const float*)d_in[3];
    const float* out_c    = (const float*)d_in[4];
    float* y = (float*)d_out;

    // Workspace layout (bytes): w1 64KB | icT 512KB | M_T 4MB
    char* ws = (char*)d_ws;
    bf16* w1  = (bf16*)ws;
    bf16* icT = (bf16*)(ws + (64 << 10));
    bf16* mtc = (bf16*)(ws + (64 << 10) + (512 << 10));

    k_setup<<<256, 256, 0, stream>>>(task_c, tensor_c, in_c, w1, icT);
    k2_mt  <<<512, 256, 0, stream>>>(out_c, w1, mtc);
    k_fused<<<512, 256, 0, stream>>>(x, icT, mtc, y);
}

// Round 8
// 283.302 us; speedup vs baseline: 1.1679x; 1.0054x over previous
//
#include <hip/hip_runtime.h>
#include <hip/hip_bf16.h>

// Reassociated Tucker pipeline (fp32 in/out; bf16 internally):
//   y[b,t,o] = sum_j Z[b,t,j] * M[t,j,o]
//     Z[b,t,j] = sum_i x[b,t,i]   * in_core[i,j]
//     M[t,j,o] = sum_k W1[t,j,k]  * out_core[o,k]
//     W1[t,j,k]= sum_m task[t,m]  * tensor[m,j,k]
//
// v7 RESUBMIT (round-7 bench died to container-acquisition failure, same
// infra signature as round 3; static audit found no hang risk). v6 schedule
// kept byte-identical; ONE new lever: per-block ROTATION of the column-window
// visit order in both phases. Rationale: both heavy streams walk 128KB
// power-of-2 row strides in lockstep (all blocks touch the same 0.5-1KB
// column window simultaneously) -> HBM channel aliasing; v6 counters
// (everything idle, 2.1 TB/s, conflicts 16K) falsified schedule/conflict
// theories. Phase-1 tiles: ktr=(kt+rot)&15 (K-sum is order-independent);
// phase-2 o-groups: gr=(g+rot)&7 (independent). Blocks now cover 8-16
// distinct column windows at any instant.

typedef __bf16 bf16;
typedef __bf16 bf16x8 __attribute__((ext_vector_type(8)));
typedef __bf16 bf16x4 __attribute__((ext_vector_type(4)));
typedef float  f32x4  __attribute__((ext_vector_type(4)));

__device__ __forceinline__ bf16x8 load_frag_bf16(const bf16* p) {
    return *reinterpret_cast<const bf16x8*>(p);
}

__device__ __forceinline__ bf16x8 load_frag_f32(const float* p) {
    f32x4 a = *reinterpret_cast<const f32x4*>(p);
    f32x4 b = *reinterpret_cast<const f32x4*>(p + 4);
    bf16x8 r;
    r[0] = (bf16)a[0]; r[1] = (bf16)a[1]; r[2] = (bf16)a[2]; r[3] = (bf16)a[3];
    r[4] = (bf16)b[0]; r[5] = (bf16)b[1]; r[6] = (bf16)b[2]; r[7] = (bf16)b[3];
    return r;
}

__device__ __forceinline__ f32x4 mfma16(bf16x8 a, bf16x8 b, f32x4 c) {
    return __builtin_amdgcn_mfma_f32_16x16x32_bf16(a, b, c, 0, 0, 0);
}

// Async global->LDS, 16B per lane. LDS dest is wave-uniform base + lane*16.
__device__ __forceinline__ void gl_lds16(const float* g, void* l) {
    __builtin_amdgcn_global_load_lds(
        (const __attribute__((address_space(1))) void*)g,
        (__attribute__((address_space(3))) void*)l, 16, 0, 0);
}

// One barrier per tile: drain staged gload_lds (+B-frag prefetch), then sync.
// Memory clobber orders LDS ops around it. NO sched_barrier (m141 lesson).
__device__ __forceinline__ void tile_bar() {
    asm volatile("s_waitcnt vmcnt(0)\n\ts_barrier" ::: "memory");
}

// ---------------------------------------------------------------- K_SETUP
// grid 256 x 256. Blocks 0..127: W1[t][j][k] = sum_m task[t][m]*tensor[m][j][k].
// Blocks 128..255: icT[j][i] = bf16(in_core[i][j]) (16B stores, 1KB runs).
__global__ __launch_bounds__(256) void k_setup(
    const float* __restrict__ task,    // [8][64]
    const float* __restrict__ tensor,  // [64][64][64] (m, j, k)
    const float* __restrict__ in_core, // [4096][64]   (i, j)
    bf16* __restrict__ w1,             // [8][64][64]  (t, j, k)
    bf16* __restrict__ icT)            // [64][4096]   (j, i)
{
    int bid = blockIdx.x;
    if (bid < 128) {
        int t    = bid >> 4;
        int idx  = (bid & 15) * 256 + threadIdx.x;  // 0..4095
        int j    = idx >> 6;
        int k    = idx & 63;                        // lanes consecutive in k
        float acc = 0.f;
        #pragma unroll 8
        for (int m = 0; m < 64; ++m)
            acc += task[t * 64 + m] * tensor[(m * 64 + j) * 64 + k];
        w1[(t * 64 + j) * 64 + k] = (bf16)acc;
    } else {
        int idx = (bid - 128) * 256 + threadIdx.x;  // 0..32767
        int i0  = (idx & 511) * 8;
        int j   = idx >> 9;
        bf16x8 v;
        #pragma unroll
        for (int s = 0; s < 8; ++s)
            v[s] = (bf16)in_core[(size_t)(i0 + s) * 64 + j];
        *reinterpret_cast<bf16x8*>(icT + (size_t)j * 4096 + i0) = v;
    }
}

// ---------------------------------------------------------------- K2
// grid 512 x 256. M_T[t][o][j] = sum_k out_core[o][k]*W1[t][j][k].
__global__ __launch_bounds__(256) void k2_mt(
    const float* __restrict__ out_core, // [4096][64] (o, k) fp32
    const bf16* __restrict__ w1,        // [8][64][64] (t, j, k)
    bf16* __restrict__ mt)              // [8][4096][64] (t, o, j)
{
    int t    = blockIdx.x >> 6;
    int ot   = blockIdx.x & 63;
    int wave = threadIdx.x >> 6;
    int lane = threadIdx.x & 63;
    int m    = lane & 15;
    int q    = lane >> 4;
    int o0   = ot * 64 + wave * 16;

    f32x4 acc[4] = {};
    #pragma unroll
    for (int kc = 0; kc < 64; kc += 32) {
        bf16x8 a = load_frag_f32(out_core + (size_t)(o0 + m) * 64 + kc + q * 8);
        #pragma unroll
        for (int nt = 0; nt < 4; ++nt) {
            bf16x8 b = load_frag_bf16(w1 + (size_t)(t * 64 + nt * 16 + m) * 64 + kc + q * 8);
            acc[nt] = mfma16(a, b, acc[nt]);
        }
    }
    #pragma unroll
    for (int nt = 0; nt < 4; ++nt) {
        #pragma unroll
        for (int r = 0; r < 4; ++r) {
            int o = o0 + q * 4 + r;                  // C/D row = quad*4 + reg
            mt[(size_t)(t * 4096 + o) * 64 + nt * 16 + m] = (bf16)acc[nt][r];
        }
    }
}

// ---------------------------------------------------------------- K_FUSED
// grid 512 x 256. Block: t = bid&7 (XCD-locked), 16 rows (b0+i)*8+t.
// Phase 1: Zb = X[16 rows][4096] * icT^T. Double-buffered gload_lds tiles
//   (16 rows x 256 f32), source-swizzled, one vmcnt(0)+s_barrier per tile.
//   TILE ORDER ROTATED per block: ktr = (kt + rot) & 15.
// Phase 2: y[16 rows][4096] = Zb * M_T[t]; slab transpose, 512B-contiguous
//   f32x4 stores. O-GROUP ORDER ROTATED per block: gr = (g + rot) & 7.
__global__ __launch_bounds__(256) void k_fused(
    const float* __restrict__ x,   // [8192][4096] fp32 (rows = b*8+t)
    const bf16* __restrict__ icT,  // [64][4096] (j, i)
    const bf16* __restrict__ mt,   // [8][4096][64] (t, o, j)
    float* __restrict__ y)         // [1024][8][4096] fp32
{
    // pool: phase 1 = two 16 KB f32 x-tiles; phase 2 = 33 KB slab.
    __shared__ __align__(16) char pool[4 * 2112 * 4];   // 33792 B
    __shared__ bf16 zb[16 * 80];                        // 2.5 KB

    float* xsf0 = (float*)pool;           // [4096] f32, tile buffer 0
    float* xsf1 = (float*)pool + 4096;    // tile buffer 1
    float* slab = (float*)pool;           // phase-2 reuse (xsf dead by then)

    int t    = blockIdx.x & 7;            // one t per XCD (round-robin dispatch)
    int bg   = blockIdx.x >> 3;           // b-group 0..63
    int b0   = bg * 16;
    int rot  = bg & 15;                   // per-block column-window rotation
    int tid  = threadIdx.x;
    int row  = tid >> 4;                  // staging row 0..15
    int cc   = (tid & 15) ^ row;          // pre-swizzled source chunk
    int wave = tid >> 6;
    int lane = tid & 63;
    int m    = lane & 15;
    int q    = lane >> 4;
    int n0   = wave * 16;                 // j-range of this wave (phase 1)

    // per-lane global source (row, swizzled chunk)
    const float* xrow = x + (size_t)((b0 + row) * 8 + t) * 4096 + cc * 4;
    const bf16*  bbas = icT + (size_t)(n0 + m) * 4096;

    // stage physical tile ktr into LDS buffer (4 x gload_lds dwordx4)
    auto stage = [&](int ktr, float* buf) {
        char* lb = (char*)buf + wave * 1024;
        const float* g = xrow + (size_t)ktr * 256;
        #pragma unroll
        for (int i = 0; i < 4; ++i)
            gl_lds16(g + i * 64, lb + i * 4096);
    };
    // prefetch physical tile ktr's 8 icT B-frags into registers
    auto loadfrags = [&](bf16x8* f, int ktr) {
        #pragma unroll
        for (int c = 0; c < 8; ++c)
            f[c] = load_frag_bf16(bbas + ktr * 256 + c * 32 + q * 8);
    };
    // 8 MFMA from buf: A-frag = row m, f32 cols c*32+q*8..+8 (inv-swizzled)
    f32x4 acc = {};
    auto compute = [&](const float* buf, const bf16x8* f) {
        #pragma unroll
        for (int c = 0; c < 8; ++c) {
            int ib = c >> 1;                        // 64-f32 col block
            int h2 = ((c & 1) * 4 + q) * 2;         // first 16B chunk
            const float* base = buf + ib * 1024 + m * 64;
            f32x4 a0 = *reinterpret_cast<const f32x4*>(base + ((h2    ) ^ m) * 4);
            f32x4 a1 = *reinterpret_cast<const f32x4*>(base + ((h2 + 1) ^ m) * 4);
            bf16x8 a;
            a[0] = (bf16)a0[0]; a[1] = (bf16)a0[1];
            a[2] = (bf16)a0[2]; a[3] = (bf16)a0[3];
            a[4] = (bf16)a1[0]; a[5] = (bf16)a1[1];
            a[6] = (bf16)a1[2]; a[7] = (bf16)a1[3];
            acc = mfma16(a, f[c], acc);
        }
    };

    // ---------------- phase 1 (tile order rotated: kt -> (kt+rot)&15) ------
    bf16x8 bfrA[8], bfrB[8];
    loadfrags(bfrA, rot);
    stage(rot, xsf0);
    tile_bar();

    #pragma unroll 1
    for (int kt = 0; kt < 16; kt += 2) {
        // even tile (buf0): stage kt+1 -> buf1, prefetch frags kt+1
        {
            int k1 = (kt + 1 + rot) & 15;
            stage(k1, xsf1);
            loadfrags(bfrB, k1);
            compute(xsf0, bfrA);
            tile_bar();
        }
        // odd tile (buf1): stage kt+2 -> buf0, prefetch frags kt+2
        if (kt + 2 < 16) {
            int k2 = (kt + 2 + rot) & 15;
            stage(k2, xsf0);
            loadfrags(bfrA, k2);
        }
        compute(xsf1, bfrB);
        tile_bar();
    }
    // acc[rr] = Z[row q*4+rr][j n0+m]  (D-row <-> A-row, D-col <-> B-row)
    #pragma unroll
    for (int rr = 0; rr < 4; ++rr)
        zb[(q * 4 + rr) * 80 + n0 + m] = (bf16)acc[rr];
    __syncthreads();                       // Zb complete; xsf dead -> slab live

    // ---------------- phase 2 (o-group order rotated: g -> (g+rot)&7) ------
    bf16x8 a_lo = *reinterpret_cast<const bf16x8*>(zb + m * 80 + q * 8);
    bf16x8 a_hi = *reinterpret_cast<const bf16x8*>(zb + m * 80 + 32 + q * 8);

    float* sw = slab + wave * 2112;               // wave-private slab
    const bf16* mbase = mt + ((size_t)t * 4096 + wave * 1024) * 64;

    #pragma unroll 1
    for (int g = 0; g < 8; ++g) {
        int gr = (g + rot) & 7;                   // rotated o-group
        f32x4 acc2[8] = {};
        #pragma unroll
        for (int nt = 0; nt < 8; ++nt) {
            const bf16* bp = mbase + (size_t)(gr * 128 + nt * 16 + m) * 64;
            bf16x8 blo = load_frag_bf16(bp + q * 8);        // L2 (XCD-local)
            bf16x8 bhi = load_frag_bf16(bp + 32 + q * 8);
            acc2[nt] = mfma16(a_lo, blo, acc2[nt]);
            acc2[nt] = mfma16(a_hi, bhi, acc2[nt]);
        }
        // transpose 16 rows x 128 o through wave-private slab
        #pragma unroll
        for (int nt = 0; nt < 8; ++nt) {
            #pragma unroll
            for (int rr = 0; rr < 4; ++rr)
                sw[(q * 4 + rr) * 132 + nt * 16 + m] = acc2[nt][rr];
        }
        #pragma unroll
        for (int p = 0; p < 8; ++p) {
            int rr = 2 * p + (lane >> 5);   // 2 rows x 512B contiguous / instr
            int cu = lane & 31;
            f32x4 d = *reinterpret_cast<const f32x4*>(sw + rr * 132 + cu * 4);
            *reinterpret_cast<f32x4*>(
                y + (size_t)((b0 + rr) * 8 + t) * 4096 + wave * 1024 + gr * 128 + cu * 4) = d;
        }
    }
}

// ----------------------------------------------------------------
extern "C" void kernel_launch(void* const* d_in, const int* in_sizes, int n_in,
                              void* d_out, int out_size, void* d_ws, size_t ws_size,
                              hipStream_t stream) {
    // setup_inputs order: x, tensor_core, task_core, in_core, out_core (all fp32)
    const float* x        = (const float*)d_in[0];
    const float* tensor_c = (const float*)d_in[1];
    const float* task_c   = (const float*)d_in[2];
    const float* in_c     = (const float*)d_in[3];
    const float* out_c    = (const float*)d_in[4];
    float* y = (float*)d_out;

    // Workspace layout (bytes): w1 64KB | icT 512KB | M_T 4MB
    char* ws = (char*)d_ws;
    bf16* w1  = (bf16*)ws;
    bf16* icT = (bf16*)(ws + (64 << 10));
    bf16* mtc = (bf16*)(ws + (64 << 10) + (512 << 10));

    k_setup<<<256, 256, 0, stream>>>(task_c, tensor_c, in_c, w1, icT);
    k2_mt  <<<512, 256, 0, stream>>>(out_c, w1, mtc);
    k_fused<<<512, 256, 0, stream>>>(x, icT, mtc, y);
}